// Round 4
// baseline (1531.354 us; speedup 1.0000x reference)
//
#include <hip/hip_runtime.h>
#include <math.h>

#define N_PTS 16384
#define KNN 20
#define NRANGE 4
#define C_RANGE (N_PTS / NRANGE)       // 4096
#define QCAP 64
#define QDS 65                          // qd stride (floats): bank = (65l+s)%32 = (l+s)%32, conflict-free
#define QIS 68                          // qix stride (bytes): 17l word-stride, gcd(17,32)=1, conflict-free

// histogram binning: b = (bits(u)>>22) - 222  -> half-octave bins (ratio sqrt(2)),
// covering [2^-16, 2^16) in 64 bins. upper_edge(b) = as_float((b+223)<<22).
#define HBIN_SHIFT 22
#define HBIN_BASE 222

// ---------------- pack x + squared norm ----------------
__global__ void pack3_kernel(const float* __restrict__ x, float4* __restrict__ xp) {
  int i = blockIdx.x * blockDim.x + threadIdx.x;
  {
    #pragma clang fp contract(off)
    float a = x[i*3+0], b = x[i*3+1], c = x[i*3+2];
    xp[i] = make_float4(a, b, c, a*a + b*b + c*c);
  }
}

__global__ void sq64_kernel(const float* __restrict__ h, float* __restrict__ sq) {
  int i = blockIdx.x * blockDim.x + threadIdx.x;
  const float4* r = (const float4*)(h + (long)i*64);
  {
    #pragma clang fp contract(off)
    float ax=0.f, ay=0.f, az=0.f, aw=0.f;
    for (int t=0; t<16; t++) {
      float4 v = r[t];
      ax += v.x*v.x; ay += v.y*v.y; az += v.z*v.z; aw += v.w*v.w;
    }
    sq[i] = (ax+ay)+(az+aw);
  }
}

// ---------------- bf16 helpers ----------------
__device__ __forceinline__ unsigned short f2bf(float f) {
  unsigned int u = __float_as_uint(f);
  unsigned int r = (u + 0x7fffu + ((u >> 16) & 1u)) >> 16;   // round-to-nearest-even
  return (unsigned short)r;
}
__device__ __forceinline__ float bf2f(unsigned short b) {
  return __uint_as_float(((unsigned int)b) << 16);
}

// ---------------- h1 -> bf16 hi plane (filter is hi-only; drain rescores exactly) ----------------
__global__ void tobf16_kernel(const float* __restrict__ h,
                              unsigned short* __restrict__ bh) {
  int g = blockIdx.x*256 + threadIdx.x;      // 262144 float4s
  float4 v = ((const float4*)h)[g];
  ushort4 hv;
  hv.x = f2bf(v.x); hv.y = f2bf(v.y); hv.z = f2bf(v.z); hv.w = f2bf(v.w);
  ((ushort4*)bh)[g] = hv;
}

// ---------------- x -> packed K=32 bf16 rows for D=3 MFMA filter ----------------
// A-row: [qh0,qh1,qh2, ql0,ql1,ql2, qh0,qh1,qh2, ql0,ql1,ql2, 0 x20]
// B-row: [ch0,ch1,ch2, ch0,ch1,ch2, cl0,cl1,cl2, cl0,cl1,cl2, 0 x20]
// => sum_k A[k]B[k] = (qh+ql).(ch+cl) with every cross term represented exactly.
__global__ void packbf3_kernel(const float* __restrict__ x,
                               unsigned short* __restrict__ xpa,
                               unsigned short* __restrict__ xpb) {
  int i = blockIdx.x*256 + threadIdx.x;   // 16384
  float v0 = x[i*3+0], v1 = x[i*3+1], v2 = x[i*3+2];
  unsigned int h0 = f2bf(v0), h1 = f2bf(v1), h2 = f2bf(v2);
  unsigned int l0 = f2bf(v0 - bf2f((unsigned short)h0));
  unsigned int l1 = f2bf(v1 - bf2f((unsigned short)h1));
  unsigned int l2 = f2bf(v2 - bf2f((unsigned short)h2));
  unsigned int ua0 = h0 | (h1<<16), ua1 = h2 | (l0<<16), ua2 = l1 | (l2<<16);
  unsigned int ub0 = h0 | (h1<<16), ub1 = h2 | (h0<<16), ub2 = h1 | (h2<<16);
  unsigned int ub3 = l0 | (l1<<16), ub4 = l2 | (l0<<16), ub5 = l1 | (l2<<16);
  uint4* pa = (uint4*)(xpa + (size_t)i*32);
  uint4* pb = (uint4*)(xpb + (size_t)i*32);
  uint4 z; z.x = 0u; z.y = 0u; z.z = 0u; z.w = 0u;
  uint4 A0; A0.x = ua0; A0.y = ua1; A0.z = ua2; A0.w = ua0;
  uint4 A1; A1.x = ua1; A1.y = ua2; A1.z = 0u;  A1.w = 0u;
  uint4 B0; B0.x = ub0; B0.y = ub1; B0.z = ub2; B0.w = ub3;
  uint4 B1; B1.x = ub4; B1.y = ub5; B1.z = 0u;  B1.w = 0u;
  pa[0] = A0; pa[1] = A1; pa[2] = z; pa[3] = z;
  pb[0] = B0; pb[1] = B1; pb[2] = z; pb[3] = z;
}

// ---------------- seed thresholds from graph-1 neighbors (exact upper bound) ----------------
__global__ __launch_bounds__(256, 2) void seed64_kernel(const float* __restrict__ h,
                                                        const float* __restrict__ sq,
                                                        const int* __restrict__ idx1,
                                                        float* __restrict__ wsd) {
  int i = blockIdx.x*256 + threadIdx.x;   // 16384
  float4 q4[16];
  const float4* qrow = (const float4*)(h + (size_t)i*64);
  #pragma unroll
  for (int t=0;t<16;t++) q4[t] = qrow[t];
  float sqi = sq[i];
  float wmax = 0.f;
  for (int k=0;k<KNN;k++) {
    int j = idx1[i*KNN+k];
    const float4* crow = (const float4*)(h + (size_t)j*64);
    float acc = 0.f;
    #pragma unroll 4
    for (int t=0;t<16;t++) {
      float4 c = crow[t];
      acc += q4[t].x*c.x; acc += q4[t].y*c.y; acc += q4[t].z*c.z; acc += q4[t].w*c.w;
    }
    float sqj = sq[j];
    float d = (sqi + sqj) - 2.0f*acc;
    d += (sqi + sqj)*3e-5f + 1e-25f;
    wmax = fmaxf(wmax, d);
  }
  wsd[i] = wmax;
}

// register top-20: replace current lex-max with (e,ei), rescan for new max.
__device__ __forceinline__ void t20_replace_rescan(float (&rd)[KNN], int (&ri)[KNN],
                                                   float &maxd, int &maxi, int &maxp,
                                                   float e, int ei) {
  #pragma unroll
  for (int k = 0; k < KNN; k++) if (k == maxp) { rd[k] = e; ri[k] = ei; }
  float md = rd[0]; int mi = ri[0]; int mp = 0;
  #pragma unroll
  for (int k = 1; k < KNN; k++) {
    bool g = (rd[k] > md) || (rd[k] == md && ri[k] > mi);
    md = g ? rd[k] : md; mi = g ? ri[k] : mi; mp = g ? k : mp;
  }
  maxd = md; maxi = mi; maxp = mp;
}

// wave-internal fence: drain outstanding LDS ops + stop compiler reordering
#define WAVE_LDS_FENCE() asm volatile("s_waitcnt lgkmcnt(0)" ::: "memory")

typedef __bf16 bf16x8 __attribute__((ext_vector_type(8)));
typedef float f32x4 __attribute__((ext_vector_type(4)));
#define MFMA16(A,B,C) __builtin_amdgcn_mfma_f32_16x16x32_bf16((A),(B),(C),0,0,0)
#define SCALE3 0.9998f
#define SCALE_HH 0.995f   // hi-only filter deflation: bf16-hi err <= 2^-8 (sq_i+sq_j) < 0.4%

// bin an inflated distance; returns [0,63]
__device__ __forceinline__ int hbin(float uu) {
  uu = fmaxf(uu, 1e-20f);
  int b = (int)(__float_as_uint(uu) >> HBIN_SHIFT) - HBIN_BASE;
  return b < 0 ? 0 : (b > 63 ? 63 : b);
}

// ---------------- knn D=64: wsd-seeded hi-only MFMA filter + exact fp32 confirm ----------------
// 16 queries/wave (4096 waves total -> 4 waves/SIMD for latency hiding).
// Filter: dd = fma(-2, a_hihi, 0.995*(sq_i+sq_j)) <= exact distance always
// (bf16-hi product error <= 2^-8 (sq_i+sq_j); deflation 0.5% > bound) => superset push set.
// Drain rescores survivors with the bit-identical exact fp32 fmaf chain.
// Structural QCAP: 16 lanes x 4 tiles = 64 pushes max per query per window.
__global__ __launch_bounds__(256, 4) void knn64_wq(const float* __restrict__ h1,
                                                   const unsigned short* __restrict__ hbh,
                                                   const float* __restrict__ sqh,
                                                   const float* __restrict__ wsd,
                                                   float* __restrict__ pd,
                                                   int* __restrict__ pi) {
  __shared__ float qd[4][16][QDS];
  __shared__ unsigned char qix[4][16][QIS];
  __shared__ float w19[4][16];
  __shared__ int   cnt[4][16];

  int tid = threadIdx.x;
  int wv = tid >> 6;
  int l  = tid & 63;
  int qb = blockIdx.x >> 2, rg = blockIdx.x & 3;
  int q0 = qb*64, c0 = rg*C_RANGE;
  int qw0 = q0 + wv*16;

  float rd[KNN]; int ri[KNN];
  #pragma unroll
  for (int k = 0; k < KNN; k++) { rd[k] = INFINITY; ri[k] = 0x7fffffff; }
  float maxd = INFINITY; int maxi = 0x7fffffff; int maxp = 0;

  float wsv = INFINITY, sqi = 0.f;
  if (l < 16) {
    wsv = wsd[qw0 + l]; sqi = sqh[qw0 + l];
    w19[wv][l] = wsv; cnt[wv][l] = 0;
  }

  int cn   = l & 15;           // fragment row selector (A row / B col / D col)
  int koff = (l >> 4) * 8;     // k-offset within 32-wide K block

  bf16x8 ah0, ah1;
  {
    size_t ar = (size_t)(qw0 + cn) * 64 + koff;
    ah0 = *(const bf16x8*)(hbh + ar);
    ah1 = *(const bf16x8*)(hbh + ar + 32);
  }

  float qsl[4], wq[4];
  #pragma unroll
  for (int v = 0; v < 4; v++)
    qsl[v] = sqh[qw0 + (l>>4)*4 + v] * SCALE_HH;
  WAVE_LDS_FENCE();
  #pragma unroll
  for (int v = 0; v < 4; v++) wq[v] = w19[wv][(l>>4)*4 + v];

  for (int win = 0; win < C_RANGE/64; win++) {
    int cw0 = c0 + win*64;
    #pragma unroll
    for (int tt = 0; tt < 4; tt++) {
      int ct = cw0 + tt*16;
      size_t br = (size_t)(ct + cn) * 64 + koff;
      bf16x8 bh0 = *(const bf16x8*)(hbh + br);
      bf16x8 bh1 = *(const bf16x8*)(hbh + br + 32);
      f32x4 z = {0.f, 0.f, 0.f, 0.f};
      f32x4 a0;
      a0 = MFMA16(ah0, bh0, z);
      a0 = MFMA16(ah1, bh1, a0);

      float csl = sqh[ct + cn] * SCALE_HH;
      #pragma unroll
      for (int v = 0; v < 4; v++) {
        float dd = fmaf(-2.f, a0[v], qsl[v] + csl);   // <= exact distance (deflated norms)
        if (dd <= wq[v]) {
          int lq = (l>>4)*4 + v;
          int slot = atomicAdd(&cnt[wv][lq], 1);
          qd[wv][lq][slot] = dd;
          qix[wv][lq][slot] = (unsigned char)(tt*16 + cn);
        }
      }
    }

    // drain: exact fp32 rescore of survivors (bit-matches original fp32 arithmetic)
    WAVE_LDS_FENCE();
    int myc = (l < 16) ? cnt[wv][l] : 0;
    if (__any(myc != 0)) {
      if (myc) {
        const float4* qr = (const float4*)(h1 + (size_t)(qw0 + l)*64);
        for (int s = 0; s < myc; s++) {
          float ea = qd[wv][l][s];
          if (ea > maxd) continue;                  // ea <= exact e, so safe skip
          int j = cw0 + (int)qix[wv][l][s];
          const float4* cr = (const float4*)(h1 + (size_t)j*64);
          float a = 0.f;
          #pragma unroll 4
          for (int t = 0; t < 16; t++) {
            float4 q = qr[t], c = cr[t];
            a = fmaf(q.x, c.x, a); a = fmaf(q.y, c.y, a);
            a = fmaf(q.z, c.z, a); a = fmaf(q.w, c.w, a);
          }
          float e = (sqi + sqh[j]) - 2.0f*a;
          if (e < maxd || (e == maxd && j < maxi))
            t20_replace_rescan(rd, ri, maxd, maxi, maxp, e, j);
        }
        cnt[wv][l] = 0;
        w19[wv][l] = fminf(maxd, wsv);
      }
      WAVE_LDS_FENCE();
      #pragma unroll
      for (int v = 0; v < 4; v++) wq[v] = w19[wv][(l>>4)*4 + v];
    }
  }

  if (l < 16) {
    size_t o = ((size_t)(qw0 + l)*NRANGE + rg)*KNN;
    for (int k = 0; k < KNN; k++) {
      float md = rd[0]; int mi = ri[0]; int mp = 0;
      #pragma unroll
      for (int t = 1; t < KNN; t++) {
        bool g = (rd[t] < md) || (rd[t] == md && ri[t] < mi);
        md = g ? rd[t] : md; mi = g ? ri[t] : mi; mp = g ? t : mp;
      }
      pd[o+k] = md; pi[o+k] = mi;
      #pragma unroll
      for (int t = 0; t < KNN; t++) if (t == mp) rd[t] = INFINITY;
    }
  }
}

// ---------------- knn D=3: subsampled-hist-seeded MFMA filter + exact fp32 confirm ----------------
// 16 queries/wave. Prologue bins inflated distances for every 4th window (1024 cands);
// cumsum>=20 at bin b over a SUBSET still implies >=20 exact range distances <=
// upper_edge(b) => valid (slightly looser) w0. Main scan identical to round-3 proven.
__global__ __launch_bounds__(256, 4) void knn3_wq(const float4* __restrict__ xp,
                                                  const unsigned short* __restrict__ xpa,
                                                  const unsigned short* __restrict__ xpb,
                                                  float* __restrict__ pd,
                                                  int* __restrict__ pi) {
  __shared__ float qd[4][16][QDS];
  __shared__ unsigned char qix[4][16][QIS];
  __shared__ float w19[4][16];
  __shared__ int   cnt[4][16];

  int tid = threadIdx.x;
  int wv = tid >> 6;
  int l  = tid & 63;
  int qb = blockIdx.x >> 2, rg = blockIdx.x & 3;
  int q0 = qb*64, c0 = rg*C_RANGE;
  int qw0 = q0 + wv*16;

  float rd[KNN]; int ri[KNN];
  #pragma unroll
  for (int k = 0; k < KNN; k++) { rd[k] = INFINITY; ri[k] = 0x7fffffff; }
  float maxd = INFINITY; int maxi = 0x7fffffff; int maxp = 0;

  float4 qv4 = make_float4(0.f, 0.f, 0.f, 0.f);
  if (l < 16) {
    cnt[wv][l] = 0;
    qv4 = xp[qw0 + l];
  }

  int cn   = l & 15;
  int koff = (l >> 4) * 8;

  bf16x8 aq = *(const bf16x8*)(xpa + (size_t)(qw0 + cn)*32 + koff);

  float qsr[4], qsp[4];
  #pragma unroll
  for (int v = 0; v < 4; v++) {
    qsr[v] = xp[qw0 + (l>>4)*4 + v].w;
    qsp[v] = qsr[v] * SCALE3;
  }

  // ---- phase 1: subsampled histogram prologue (every 4th window) ----
  unsigned int* hw = (unsigned int*)&qd[wv][0][0];   // [16][QDS] uint hist, per wave
  for (int t = l; t < 16*QDS; t += 64) hw[t] = 0u;
  WAVE_LDS_FENCE();

  for (int win = 0; win < C_RANGE/64; win += 4) {
    int cw0 = c0 + win*64;
    #pragma unroll
    for (int tt = 0; tt < 4; tt++) {
      int ct = cw0 + tt*16;
      bf16x8 bb = *(const bf16x8*)(xpb + (size_t)(ct + cn)*32 + koff);
      f32x4 z = {0.f, 0.f, 0.f, 0.f};
      f32x4 a0 = MFMA16(aq, bb, z);
      float csr = xp[ct + cn].w;
      #pragma unroll
      for (int v = 0; v < 4; v++) {
        float uu = fmaf(-2.f, a0[v], (qsr[v] + csr) * 1.0002f);  // >= exact distance
        int lq = (l>>4)*4 + v;
        atomicAdd(&hw[lq*QDS + hbin(uu)], 1u);
      }
    }
  }
  WAVE_LDS_FENCE();

  float wsv = INFINITY;
  if (l < 16) {
    unsigned int c = 0; int bsel = 64;
    for (int b = 0; b < 64; b++) {
      c += hw[l*QDS + b];
      if (bsel == 64 && c >= 20u) bsel = b;
    }
    if (bsel < 63)
      wsv = __uint_as_float((unsigned int)(bsel + HBIN_BASE + 1) << HBIN_SHIFT);
    w19[wv][l] = wsv;
  }
  WAVE_LDS_FENCE();
  float wq[4];
  #pragma unroll
  for (int v = 0; v < 4; v++) wq[v] = w19[wv][(l>>4)*4 + v];

  // ---- phase 2: main scan ----
  for (int win = 0; win < C_RANGE/64; win++) {
    int cw0 = c0 + win*64;
    #pragma unroll
    for (int tt = 0; tt < 4; tt++) {
      int ct = cw0 + tt*16;
      bf16x8 bb = *(const bf16x8*)(xpb + (size_t)(ct + cn)*32 + koff);
      f32x4 z = {0.f, 0.f, 0.f, 0.f};
      f32x4 a0 = MFMA16(aq, bb, z);
      float csp = xp[ct + cn].w * SCALE3;
      #pragma unroll
      for (int v = 0; v < 4; v++) {
        float dd = fmaf(-2.f, a0[v], qsp[v] + csp);     // <= exact distance
        if (dd <= wq[v]) {
          int lq = (l>>4)*4 + v;
          int slot = atomicAdd(&cnt[wv][lq], 1);
          qd[wv][lq][slot] = dd;
          qix[wv][lq][slot] = (unsigned char)(tt*16 + cn);
        }
      }
    }

    // drain: exact fp32 rescore (bit-identical to original knn3 distance expression)
    WAVE_LDS_FENCE();
    int myc = (l < 16) ? cnt[wv][l] : 0;
    if (__any(myc != 0)) {
      if (myc) {
        for (int s = 0; s < myc; s++) {
          float ea = qd[wv][l][s];
          if (ea > maxd) continue;
          int j = cw0 + (int)qix[wv][l][s];
          float4 cv4 = xp[j];
          float e = (qv4.w + cv4.w)
                  - 2.0f*(qv4.x*cv4.x + qv4.y*cv4.y + qv4.z*cv4.z);
          if (e < maxd || (e == maxd && j < maxi))
            t20_replace_rescan(rd, ri, maxd, maxi, maxp, e, j);
        }
        cnt[wv][l] = 0;
        w19[wv][l] = fminf(maxd, wsv);
      }
      WAVE_LDS_FENCE();
      #pragma unroll
      for (int v = 0; v < 4; v++) wq[v] = w19[wv][(l>>4)*4 + v];
    }
  }

  if (l < 16) {
    size_t o = ((size_t)(qw0 + l)*NRANGE + rg)*KNN;
    for (int k = 0; k < KNN; k++) {
      float md = rd[0]; int mi = ri[0]; int mp = 0;
      #pragma unroll
      for (int t = 1; t < KNN; t++) {
        bool g = (rd[t] < md) || (rd[t] == md && ri[t] < mi);
        md = g ? rd[t] : md; mi = g ? ri[t] : mi; mp = g ? t : mp;
      }
      pd[o+k] = md; pi[o+k] = mi;
      #pragma unroll
      for (int t = 0; t < KNN; t++) if (t == mp) rd[t] = INFINITY;
    }
  }
}

// ---------------- merge NRANGE sorted partial lists -> top-20 ----------------
__global__ void knn_merge_kernel(const float* __restrict__ pd, const int* __restrict__ pi,
                                 int* __restrict__ out_idx) {
  int qi = blockIdx.x*256 + threadIdx.x;
  const float* bd = pd + (size_t)qi*NRANGE*KNN;
  const int*   bi = pi + (size_t)qi*NRANGE*KNN;
  int ptr[NRANGE];
  #pragma unroll
  for (int r=0;r<NRANGE;r++) ptr[r] = 0;
  for (int k = 0; k < KNN; k++) {
    float best = INFINITY; int besti = 0x7fffffff; int br = 0;
    #pragma unroll
    for (int r = 0; r < NRANGE; r++) {
      float d = bd[r*KNN + ptr[r]];
      int   ii = bi[r*KNN + ptr[r]];
      bool better = (ptr[r] < KNN) && (d < best || (d == best && ii < besti));
      if (better) { best = d; besti = ii; br = r; }
    }
    #pragma unroll
    for (int r=0;r<NRANGE;r++) ptr[r] += (r == br) ? 1 : 0;
    out_idx[qi*KNN + k] = besti;
  }
}

// ---------------- edge_conv1 precompute ----------------
__global__ void cg1_kernel(const float* __restrict__ x, const float* __restrict__ W1,
                           const float* __restrict__ b1,
                           float* __restrict__ C1, float* __restrict__ G1) {
  int gid = blockIdx.x*256 + threadIdx.x;   // 16384*64
  int i = gid >> 6, c = gid & 63;
  float x0 = x[i*3+0], x1 = x[i*3+1], x2 = x[i*3+2];
  float wt0 = W1[0*64+c], wt1 = W1[1*64+c], wt2 = W1[2*64+c];
  float wb0 = W1[3*64+c], wb1 = W1[4*64+c], wb2 = W1[5*64+c];
  C1[gid] = x0*(wt0-wb0) + x1*(wt1-wb1) + x2*(wt2-wb2) + b1[c];
  G1[gid] = x0*wb0 + x1*wb1 + x2*wb2;
}

// ---------------- gather + max + relu ----------------
template<int C>
__global__ void maxrelu_kernel(const float* __restrict__ Ci, const float* __restrict__ G,
                               const int* __restrict__ idx, float* __restrict__ out) {
  int gid = blockIdx.x*256 + threadIdx.x;
  int i = gid / C, c = gid % C;
  float base = Ci[gid];
  float m = -INFINITY;
  for (int j=0; j<KNN; j++) {
    int jj = idx[i*KNN + j];
    m = fmaxf(m, base + G[(long)jj*C + c]);
  }
  out[gid] = fmaxf(m, 0.0f);
}

// ---------------- W2 diff ----------------
__global__ void wd2_kernel(const float* __restrict__ W2, float* __restrict__ Wd) {
  int gid = blockIdx.x*256 + threadIdx.x;   // 64*128
  int d = gid >> 7, c = gid & 127;
  Wd[gid] = W2[d*128+c] - W2[(d+64)*128+c];
}

// ---------------- edge_conv2 precompute ----------------
__global__ void cg2_kernel(const float* __restrict__ h1, const float* __restrict__ W2,
                           const float* __restrict__ Wd, const float* __restrict__ b2,
                           float* __restrict__ C2, float* __restrict__ G2) {
  int gid = blockIdx.x*256 + threadIdx.x;   // 16384*128
  int i = gid >> 7, c = gid & 127;
  float a = 0.f, g = 0.f;
  for (int d=0; d<64; d++) {
    float hv = h1[i*64 + d];
    a += hv * Wd[d*128 + c];
    g += hv * W2[(d+64)*128 + c];
  }
  C2[gid] = a + b2[c];
  G2[gid] = g;
}

// ---------------- fc1 (relu) ----------------
__global__ void fc1_kernel(const float* __restrict__ h2, const float* __restrict__ w,
                           const float* __restrict__ b, float* __restrict__ out) {
  int gid = blockIdx.x*256 + threadIdx.x;   // 16384*128
  int i = gid >> 7, c = gid & 127;
  float a = 0.f;
  for (int d=0; d<128; d++) a += h2[i*128+d] * w[d*128+c];
  out[gid] = fmaxf(a + b[c], 0.0f);
}

// ---------------- fc2 ----------------
__global__ void fc2_kernel(const float* __restrict__ f1, const float* __restrict__ w,
                           const float* __restrict__ b, float* __restrict__ out) {
  int gid = blockIdx.x*256 + threadIdx.x;   // 16384*40
  int i = gid / 40, c = gid - i*40;
  float a = 0.f;
  for (int d=0; d<128; d++) a += f1[i*128+d] * w[d*40+c];
  out[gid] = a + b[c];
}

extern "C" void kernel_launch(void* const* d_in, const int* in_sizes, int n_in,
                              void* d_out, int out_size, void* d_ws, size_t ws_size,
                              hipStream_t stream) {
  (void)in_sizes; (void)n_in; (void)out_size; (void)ws_size;
  const float* x     = (const float*)d_in[0];
  const float* W1    = (const float*)d_in[1];
  const float* b1    = (const float*)d_in[2];
  const float* W2    = (const float*)d_in[3];
  const float* b2    = (const float*)d_in[4];
  const float* fc1_w = (const float*)d_in[5];
  const float* fc1_b = (const float*)d_in[6];
  const float* fc2_w = (const float*)d_in[7];
  const float* fc2_b = (const float*)d_in[8];
  float* out = (float*)d_out;

  // ---- workspace (31.03 MB total, lifetime-disjoint aliasing) ----
  char* ws = (char*)d_ws;
  float4* xp4 = (float4*)(ws + 0);          // 262144
  float*  sqh = (float*) (ws + 262144);     // 65536
  int*    idx = (int*)   (ws + 327680);     // 1310720
  float*  Wd2 = (float*) (ws + 1638400);    // 32768
  float*  h1  = (float*) (ws + 1671168);    // 4194304  -> 5865472
  unsigned short* xpa = (unsigned short*)(ws + 1671168); // 1MB, dead before h1 written
  unsigned short* xpb = (unsigned short*)(ws + 2719744); // 1MB, dead before h1 written
  unsigned short* hbh = (unsigned short*)(ws + 5865472); // 2097152 -> 7962624
  float*  wsd = (float*) (ws + 10059776);   // 65536    (aliases h2-tail; dead then)
  float*  h2  = (float*) (ws + 5865472);    // 8388608  -> 14254080
  float*  A   = (float*) (ws + 14254080);   // 8388608  -> 22642688
  float*  C1  = A;
  float*  G1  = (float*) (ws + 14254080 + 4194304);
  float*  C2  = A;
  float*  f1  = A;
  float*  G2  = (float*) (ws + 22642688);   // 8388608  -> 31031296
  int*    pi  = (int*)   (ws + 14254080);   // 5.25MB (aliases A; A dead during knn phases)
  float*  pd  = (float*) (ws + 22642688);   // 5.25MB (aliases G2; G2 dead during knn phases)

  pack3_kernel <<<64,   256, 0, stream>>>(x, xp4);
  packbf3_kernel<<<64,  256, 0, stream>>>(x, xpa, xpb);
  knn3_wq      <<<1024, 256, 0, stream>>>(xp4, xpa, xpb, pd, pi);
  knn_merge_kernel<<<64,256, 0, stream>>>(pd, pi, idx);
  cg1_kernel   <<<4096, 256, 0, stream>>>(x, W1, b1, C1, G1);
  maxrelu_kernel<64> <<<4096, 256, 0, stream>>>(C1, G1, idx, h1);
  tobf16_kernel<<<1024, 256, 0, stream>>>(h1, hbh);
  sq64_kernel  <<<64,   256, 0, stream>>>(h1, sqh);
  seed64_kernel<<<64,   256, 0, stream>>>(h1, sqh, idx, wsd);
  knn64_wq     <<<1024, 256, 0, stream>>>(h1, hbh, sqh, wsd, pd, pi);
  knn_merge_kernel<<<64,256, 0, stream>>>(pd, pi, idx);
  wd2_kernel   <<<32,   256, 0, stream>>>(W2, Wd2);
  cg2_kernel   <<<8192, 256, 0, stream>>>(h1, W2, Wd2, b2, C2, G2);
  maxrelu_kernel<128><<<8192, 256, 0, stream>>>(C2, G2, idx, h2);
  fc1_kernel   <<<8192, 256, 0, stream>>>(h2, fc1_w, fc1_b, f1);
  fc2_kernel   <<<2560, 256, 0, stream>>>(f1, fc2_w, fc2_b, out);
}

// Round 5
// 1198.325 us; speedup vs baseline: 1.2779x; 1.2779x over previous
//
#include <hip/hip_runtime.h>
#include <math.h>

#define N_PTS 16384
#define KNN 20
#define NRANGE 4
#define C_RANGE (N_PTS / NRANGE)       // 4096
#define QCAP 128                        // structural: 16 lanes x 8 tiles per window
#define QQS 129                         // queue stride (uints): 129 mod 32 = 1, conflict-free

// histogram binning: b = (bits(u)>>22) - 222  -> half-octave bins (ratio sqrt(2)),
// covering [2^-16, 2^16) in 64 bins. upper_edge(b) = as_float((b+223)<<22).
#define HBIN_SHIFT 22
#define HBIN_BASE 222

// ---------------- pack x + squared norm ----------------
__global__ void pack3_kernel(const float* __restrict__ x, float4* __restrict__ xp) {
  int i = blockIdx.x * blockDim.x + threadIdx.x;
  {
    #pragma clang fp contract(off)
    float a = x[i*3+0], b = x[i*3+1], c = x[i*3+2];
    xp[i] = make_float4(a, b, c, a*a + b*b + c*c);
  }
}

__global__ void sq64_kernel(const float* __restrict__ h, float* __restrict__ sq) {
  int i = blockIdx.x * blockDim.x + threadIdx.x;
  const float4* r = (const float4*)(h + (long)i*64);
  {
    #pragma clang fp contract(off)
    float ax=0.f, ay=0.f, az=0.f, aw=0.f;
    for (int t=0; t<16; t++) {
      float4 v = r[t];
      ax += v.x*v.x; ay += v.y*v.y; az += v.z*v.z; aw += v.w*v.w;
    }
    sq[i] = (ax+ay)+(az+aw);
  }
}

// ---------------- bf16 helpers ----------------
__device__ __forceinline__ unsigned short f2bf(float f) {
  unsigned int u = __float_as_uint(f);
  unsigned int r = (u + 0x7fffu + ((u >> 16) & 1u)) >> 16;   // round-to-nearest-even
  return (unsigned short)r;
}
__device__ __forceinline__ float bf2f(unsigned short b) {
  return __uint_as_float(((unsigned int)b) << 16);
}

// ---------------- h1 -> bf16 hi plane (filter is hi-only; drain rescores exactly) ----------------
__global__ void tobf16_kernel(const float* __restrict__ h,
                              unsigned short* __restrict__ bh) {
  int g = blockIdx.x*256 + threadIdx.x;      // 262144 float4s
  float4 v = ((const float4*)h)[g];
  ushort4 hv;
  hv.x = f2bf(v.x); hv.y = f2bf(v.y); hv.z = f2bf(v.z); hv.w = f2bf(v.w);
  ((ushort4*)bh)[g] = hv;
}

// ---------------- x -> packed K=32 bf16 rows for D=3 MFMA filter ----------------
// A-row: [qh0,qh1,qh2, ql0,ql1,ql2, qh0,qh1,qh2, ql0,ql1,ql2, 0 x20]
// B-row: [ch0,ch1,ch2, ch0,ch1,ch2, cl0,cl1,cl2, cl0,cl1,cl2, 0 x20]
// => sum_k A[k]B[k] = (qh+ql).(ch+cl) with every cross term represented exactly.
__global__ void packbf3_kernel(const float* __restrict__ x,
                               unsigned short* __restrict__ xpa,
                               unsigned short* __restrict__ xpb) {
  int i = blockIdx.x*256 + threadIdx.x;   // 16384
  float v0 = x[i*3+0], v1 = x[i*3+1], v2 = x[i*3+2];
  unsigned int h0 = f2bf(v0), h1 = f2bf(v1), h2 = f2bf(v2);
  unsigned int l0 = f2bf(v0 - bf2f((unsigned short)h0));
  unsigned int l1 = f2bf(v1 - bf2f((unsigned short)h1));
  unsigned int l2 = f2bf(v2 - bf2f((unsigned short)h2));
  unsigned int ua0 = h0 | (h1<<16), ua1 = h2 | (l0<<16), ua2 = l1 | (l2<<16);
  unsigned int ub0 = h0 | (h1<<16), ub1 = h2 | (h0<<16), ub2 = h1 | (h2<<16);
  unsigned int ub3 = l0 | (l1<<16), ub4 = l2 | (l0<<16), ub5 = l1 | (l2<<16);
  uint4* pa = (uint4*)(xpa + (size_t)i*32);
  uint4* pb = (uint4*)(xpb + (size_t)i*32);
  uint4 z; z.x = 0u; z.y = 0u; z.z = 0u; z.w = 0u;
  uint4 A0; A0.x = ua0; A0.y = ua1; A0.z = ua2; A0.w = ua0;
  uint4 A1; A1.x = ua1; A1.y = ua2; A1.z = 0u;  A1.w = 0u;
  uint4 B0; B0.x = ub0; B0.y = ub1; B0.z = ub2; B0.w = ub3;
  uint4 B1; B1.x = ub4; B1.y = ub5; B1.z = 0u;  B1.w = 0u;
  pa[0] = A0; pa[1] = A1; pa[2] = z; pa[3] = z;
  pb[0] = B0; pb[1] = B1; pb[2] = z; pb[3] = z;
}

// ---------------- seed thresholds from graph-1 neighbors (exact upper bound) ----------------
__global__ __launch_bounds__(256, 2) void seed64_kernel(const float* __restrict__ h,
                                                        const float* __restrict__ sq,
                                                        const int* __restrict__ idx1,
                                                        float* __restrict__ wsd) {
  int i = blockIdx.x*256 + threadIdx.x;   // 16384
  float4 q4[16];
  const float4* qrow = (const float4*)(h + (size_t)i*64);
  #pragma unroll
  for (int t=0;t<16;t++) q4[t] = qrow[t];
  float sqi = sq[i];
  float wmax = 0.f;
  for (int k=0;k<KNN;k++) {
    int j = idx1[i*KNN+k];
    const float4* crow = (const float4*)(h + (size_t)j*64);
    float acc = 0.f;
    #pragma unroll 4
    for (int t=0;t<16;t++) {
      float4 c = crow[t];
      acc += q4[t].x*c.x; acc += q4[t].y*c.y; acc += q4[t].z*c.z; acc += q4[t].w*c.w;
    }
    float sqj = sq[j];
    float d = (sqi + sqj) - 2.0f*acc;
    d += (sqi + sqj)*3e-5f + 1e-25f;
    wmax = fmaxf(wmax, d);
  }
  wsd[i] = wmax;
}

// register top-20: replace current lex-max with (e,ei), rescan for new max.
__device__ __forceinline__ void t20_replace_rescan(float (&rd)[KNN], int (&ri)[KNN],
                                                   float &maxd, int &maxi, int &maxp,
                                                   float e, int ei) {
  #pragma unroll
  for (int k = 0; k < KNN; k++) if (k == maxp) { rd[k] = e; ri[k] = ei; }
  float md = rd[0]; int mi = ri[0]; int mp = 0;
  #pragma unroll
  for (int k = 1; k < KNN; k++) {
    bool g = (rd[k] > md) || (rd[k] == md && ri[k] > mi);
    md = g ? rd[k] : md; mi = g ? ri[k] : mi; mp = g ? k : mp;
  }
  maxd = md; maxi = mi; maxp = mp;
}

// wave-internal fence: drain outstanding LDS ops + stop compiler reordering.
// NOTE: lgkmcnt only — global loads issued before this stay in flight (prefetch survives).
#define WAVE_LDS_FENCE() asm volatile("s_waitcnt lgkmcnt(0)" ::: "memory")

typedef __bf16 bf16x8 __attribute__((ext_vector_type(8)));
typedef float f32x4 __attribute__((ext_vector_type(4)));
#define MFMA16(A,B,C) __builtin_amdgcn_mfma_f32_16x16x32_bf16((A),(B),(C),0,0,0)
#define SCALE3 0.9998f
#define SCALE_HH 0.995f   // hi-only deflation: RNE bf16 product err <= 2^-8, 2x term < 0.4%

// bin an inflated distance; returns [0,63]
__device__ __forceinline__ int hbin(float uu) {
  uu = fmaxf(uu, 1e-20f);
  int b = (int)(__float_as_uint(uu) >> HBIN_SHIFT) - HBIN_BASE;
  return b < 0 ? 0 : (b > 63 ? 63 : b);
}

// pack (bf16-floor(max(dd,0)) << 16) | idx  -- upper half is a lower bound of exact e
__device__ __forceinline__ unsigned int packq(float dd, int idx) {
  return (__float_as_uint(fmaxf(dd, 0.f)) & 0xffff0000u) | (unsigned int)idx;
}

// ---------------- knn D=64: wsd-seeded hi-only MFMA filter + exact fp32 confirm ----------------
// 2 waves/block (128 thr), 32 queries/wave, 128-cand windows (8 tiles), register prefetch
// of next window's tiles 0-3 issued BEFORE the drain fence (vmcnt unaffected by lgkmcnt).
// Queue: packed uint (bf16-floor lower bound | idx), QCAP=128 structural (16 lanes x 8 tiles).
// Drain rescores survivors with the bit-identical exact fp32 fmaf chain.
__global__ __launch_bounds__(128, 2) void knn64_wq(const float* __restrict__ h1,
                                                   const unsigned short* __restrict__ hbh,
                                                   const float* __restrict__ sqh,
                                                   const float* __restrict__ wsd,
                                                   float* __restrict__ pd,
                                                   int* __restrict__ pi) {
  __shared__ unsigned int qq[2][32][QQS];
  __shared__ float w19[2][32];
  __shared__ int   cnt[2][32];

  int tid = threadIdx.x;
  int wv = tid >> 6;
  int l  = tid & 63;
  int qb = blockIdx.x >> 2, rg = blockIdx.x & 3;
  int q0 = qb*64, c0 = rg*C_RANGE;
  int qw0 = q0 + wv*32;

  float rd[KNN]; int ri[KNN];
  #pragma unroll
  for (int k = 0; k < KNN; k++) { rd[k] = INFINITY; ri[k] = 0x7fffffff; }
  float maxd = INFINITY; int maxi = 0x7fffffff; int maxp = 0;

  float wsv = INFINITY, sqi = 0.f;
  if (l < 32) {
    wsv = wsd[qw0 + l]; sqi = sqh[qw0 + l];
    w19[wv][l] = wsv; cnt[wv][l] = 0;
  }

  int cn   = l & 15;           // fragment row selector
  int koff = (l >> 4) * 8;     // k-offset within 32-wide K block

  bf16x8 a00, a01, a10, a11;   // A fragments: 2 query groups, hi-only
  {
    size_t ar = (size_t)(qw0 + cn) * 64 + koff;
    a00 = *(const bf16x8*)(hbh + ar);
    a01 = *(const bf16x8*)(hbh + ar + 32);
    size_t br = (size_t)(qw0 + 16 + cn) * 64 + koff;
    a10 = *(const bf16x8*)(hbh + br);
    a11 = *(const bf16x8*)(hbh + br + 32);
  }

  float qsl[8], wq[8];
  #pragma unroll
  for (int v = 0; v < 8; v++)
    qsl[v] = sqh[qw0 + (v>>2)*16 + (l>>4)*4 + (v&3)] * SCALE_HH;
  WAVE_LDS_FENCE();
  #pragma unroll
  for (int v = 0; v < 8; v++) wq[v] = w19[wv][(v>>2)*16 + (l>>4)*4 + (v&3)];

  bf16x8 Bp[8]; float Cp[4];   // prefetched tiles 0..3 of current window

  #define LOADA64(WIN) do { int cw_ = c0 + (WIN)*128;                      \
    _Pragma("unroll")                                                      \
    for (int t_ = 0; t_ < 4; t_++) {                                       \
      size_t br_ = (size_t)(cw_ + t_*16 + cn) * 64 + koff;                 \
      Bp[2*t_]   = *(const bf16x8*)(hbh + br_);                            \
      Bp[2*t_+1] = *(const bf16x8*)(hbh + br_ + 32);                       \
      Cp[t_] = sqh[cw_ + t_*16 + cn];                                      \
    } } while (0)

  LOADA64(0);
  for (int win = 0; win < 32; win++) {
    int cw0 = c0 + win*128;
    // issue tiles 4..7 now (latency hidden under tiles 0..3 compute)
    bf16x8 Bq[8]; float Cq[4];
    #pragma unroll
    for (int t = 0; t < 4; t++) {
      size_t br = (size_t)(cw0 + (t+4)*16 + cn) * 64 + koff;
      Bq[2*t]   = *(const bf16x8*)(hbh + br);
      Bq[2*t+1] = *(const bf16x8*)(hbh + br + 32);
      Cq[t] = sqh[cw0 + (t+4)*16 + cn];
    }
    #pragma unroll
    for (int t = 0; t < 8; t++) {
      bf16x8 b0 = (t < 4) ? Bp[2*t]   : Bq[2*(t-4)];
      bf16x8 b1 = (t < 4) ? Bp[2*t+1] : Bq[2*(t-4)+1];
      f32x4 z = {0.f, 0.f, 0.f, 0.f};
      f32x4 d0 = MFMA16(a00, b0, z); d0 = MFMA16(a01, b1, d0);
      f32x4 d1 = MFMA16(a10, b0, z); d1 = MFMA16(a11, b1, d1);
      float csl = ((t < 4) ? Cp[t] : Cq[t-4]) * SCALE_HH;
      #pragma unroll
      for (int v = 0; v < 8; v++) {
        float av = (v < 4) ? d0[v] : d1[v-4];
        float dd = fmaf(-2.f, av, qsl[v] + csl);    // <= exact distance (deflated)
        if (dd <= wq[v]) {
          int lq = (v>>2)*16 + (l>>4)*4 + (v&3);
          int slot = atomicAdd(&cnt[wv][lq], 1);
          qq[wv][lq][slot] = packq(dd, t*16 + cn);
        }
      }
    }
    if (win < 31) LOADA64(win+1);   // prefetch BEFORE fence: stays in flight across drain

    WAVE_LDS_FENCE();
    int myc = (l < 32) ? cnt[wv][l] : 0;
    if (__any(myc != 0)) {
      if (myc) {
        const float4* qr = (const float4*)(h1 + (size_t)(qw0 + l)*64);
        for (int s = 0; s < myc; s++) {
          unsigned int pk = qq[wv][l][s];
          float ea = __uint_as_float(pk & 0xffff0000u);
          if (ea > maxd) continue;                  // ea <= exact e, safe skip
          int j = cw0 + (int)(pk & 0xffu);
          const float4* cr = (const float4*)(h1 + (size_t)j*64);
          float a = 0.f;
          #pragma unroll 4
          for (int t = 0; t < 16; t++) {
            float4 q = qr[t], c = cr[t];
            a = fmaf(q.x, c.x, a); a = fmaf(q.y, c.y, a);
            a = fmaf(q.z, c.z, a); a = fmaf(q.w, c.w, a);
          }
          float e = (sqi + sqh[j]) - 2.0f*a;
          if (e < maxd || (e == maxd && j < maxi))
            t20_replace_rescan(rd, ri, maxd, maxi, maxp, e, j);
        }
        cnt[wv][l] = 0;
        w19[wv][l] = fminf(maxd, wsv);
      }
      WAVE_LDS_FENCE();
      #pragma unroll
      for (int v = 0; v < 8; v++) wq[v] = w19[wv][(v>>2)*16 + (l>>4)*4 + (v&3)];
    }
  }
  #undef LOADA64

  if (l < 32) {
    size_t o = ((size_t)(qw0 + l)*NRANGE + rg)*KNN;
    for (int k = 0; k < KNN; k++) {
      float md = rd[0]; int mi = ri[0]; int mp = 0;
      #pragma unroll
      for (int t = 1; t < KNN; t++) {
        bool g = (rd[t] < md) || (rd[t] == md && ri[t] < mi);
        md = g ? rd[t] : md; mi = g ? ri[t] : mi; mp = g ? t : mp;
      }
      pd[o+k] = md; pi[o+k] = mi;
      #pragma unroll
      for (int t = 0; t < KNN; t++) if (t == mp) rd[t] = INFINITY;
    }
  }
}

// ---------------- knn D=3: subsampled-hist seed + same pipelined scan ----------------
__global__ __launch_bounds__(128, 2) void knn3_wq(const float4* __restrict__ xp,
                                                  const unsigned short* __restrict__ xpa,
                                                  const unsigned short* __restrict__ xpb,
                                                  float* __restrict__ pd,
                                                  int* __restrict__ pi) {
  __shared__ unsigned int qq[2][32][QQS];
  __shared__ float w19[2][32];
  __shared__ int   cnt[2][32];

  int tid = threadIdx.x;
  int wv = tid >> 6;
  int l  = tid & 63;
  int qb = blockIdx.x >> 2, rg = blockIdx.x & 3;
  int q0 = qb*64, c0 = rg*C_RANGE;
  int qw0 = q0 + wv*32;

  float rd[KNN]; int ri[KNN];
  #pragma unroll
  for (int k = 0; k < KNN; k++) { rd[k] = INFINITY; ri[k] = 0x7fffffff; }
  float maxd = INFINITY; int maxi = 0x7fffffff; int maxp = 0;

  float4 qv4 = make_float4(0.f, 0.f, 0.f, 0.f);
  if (l < 32) { cnt[wv][l] = 0; qv4 = xp[qw0 + l]; }

  int cn   = l & 15;
  int koff = (l >> 4) * 8;

  bf16x8 aq0 = *(const bf16x8*)(xpa + (size_t)(qw0 + cn)*32 + koff);
  bf16x8 aq1 = *(const bf16x8*)(xpa + (size_t)(qw0 + 16 + cn)*32 + koff);

  float qsr[8], qsp[8];
  #pragma unroll
  for (int v = 0; v < 8; v++) {
    qsr[v] = xp[qw0 + (v>>2)*16 + (l>>4)*4 + (v&3)].w;
    qsp[v] = qsr[v] * SCALE3;
  }

  // ---- phase 1: subsampled histogram (every 4th window = 1024 cands), aliased on qq ----
  unsigned int* hw = &qq[wv][0][0];   // [32][QQS]
  for (int t = l; t < 32*QQS; t += 64) hw[t] = 0u;
  WAVE_LDS_FENCE();

  for (int win = 0; win < 32; win += 4) {
    int cw0 = c0 + win*128;
    #pragma unroll
    for (int t = 0; t < 8; t++) {
      int ct = cw0 + t*16;
      bf16x8 bb = *(const bf16x8*)(xpb + (size_t)(ct + cn)*32 + koff);
      f32x4 z = {0.f, 0.f, 0.f, 0.f};
      f32x4 d0 = MFMA16(aq0, bb, z);
      f32x4 d1 = MFMA16(aq1, bb, z);
      float csr = xp[ct + cn].w;
      #pragma unroll
      for (int v = 0; v < 8; v++) {
        float av = (v < 4) ? d0[v] : d1[v-4];
        float uu = fmaf(-2.f, av, (qsr[v] + csr) * 1.0002f);  // >= exact distance
        int lq = (v>>2)*16 + (l>>4)*4 + (v&3);
        atomicAdd(&hw[lq*QQS + hbin(uu)], 1u);
      }
    }
  }
  WAVE_LDS_FENCE();

  float wsv = INFINITY;
  if (l < 32) {
    unsigned int c = 0; int bsel = 64;
    for (int b = 0; b < 64; b++) {
      c += hw[l*QQS + b];
      if (bsel == 64 && c >= 20u) bsel = b;
    }
    if (bsel < 63)
      wsv = __uint_as_float((unsigned int)(bsel + HBIN_BASE + 1) << HBIN_SHIFT);
    w19[wv][l] = wsv;
    cnt[wv][l] = 0;
  }
  WAVE_LDS_FENCE();
  float wq[8];
  #pragma unroll
  for (int v = 0; v < 8; v++) wq[v] = w19[wv][(v>>2)*16 + (l>>4)*4 + (v&3)];

  // ---- phase 2: pipelined main scan ----
  bf16x8 Bp[4]; float Cp[4];

  #define LOADA3(WIN) do { int cw_ = c0 + (WIN)*128;                       \
    _Pragma("unroll")                                                      \
    for (int t_ = 0; t_ < 4; t_++) {                                       \
      int ct_ = cw_ + t_*16;                                               \
      Bp[t_] = *(const bf16x8*)(xpb + (size_t)(ct_ + cn)*32 + koff);       \
      Cp[t_] = xp[ct_ + cn].w;                                             \
    } } while (0)

  LOADA3(0);
  for (int win = 0; win < 32; win++) {
    int cw0 = c0 + win*128;
    bf16x8 Bq[4]; float Cq[4];
    #pragma unroll
    for (int t = 0; t < 4; t++) {
      int ct = cw0 + (t+4)*16;
      Bq[t] = *(const bf16x8*)(xpb + (size_t)(ct + cn)*32 + koff);
      Cq[t] = xp[ct + cn].w;
    }
    #pragma unroll
    for (int t = 0; t < 8; t++) {
      bf16x8 bb = (t < 4) ? Bp[t] : Bq[t-4];
      f32x4 z = {0.f, 0.f, 0.f, 0.f};
      f32x4 d0 = MFMA16(aq0, bb, z);
      f32x4 d1 = MFMA16(aq1, bb, z);
      float csp = ((t < 4) ? Cp[t] : Cq[t-4]) * SCALE3;
      #pragma unroll
      for (int v = 0; v < 8; v++) {
        float av = (v < 4) ? d0[v] : d1[v-4];
        float dd = fmaf(-2.f, av, qsp[v] + csp);    // <= exact distance
        if (dd <= wq[v]) {
          int lq = (v>>2)*16 + (l>>4)*4 + (v&3);
          int slot = atomicAdd(&cnt[wv][lq], 1);
          qq[wv][lq][slot] = packq(dd, t*16 + cn);
        }
      }
    }
    if (win < 31) LOADA3(win+1);   // prefetch before fence

    WAVE_LDS_FENCE();
    int myc = (l < 32) ? cnt[wv][l] : 0;
    if (__any(myc != 0)) {
      if (myc) {
        for (int s = 0; s < myc; s++) {
          unsigned int pk = qq[wv][l][s];
          float ea = __uint_as_float(pk & 0xffff0000u);
          if (ea > maxd) continue;
          int j = cw0 + (int)(pk & 0xffu);
          float4 cv4 = xp[j];
          float e = (qv4.w + cv4.w)
                  - 2.0f*(qv4.x*cv4.x + qv4.y*cv4.y + qv4.z*cv4.z);
          if (e < maxd || (e == maxd && j < maxi))
            t20_replace_rescan(rd, ri, maxd, maxi, maxp, e, j);
        }
        cnt[wv][l] = 0;
        w19[wv][l] = fminf(maxd, wsv);
      }
      WAVE_LDS_FENCE();
      #pragma unroll
      for (int v = 0; v < 8; v++) wq[v] = w19[wv][(v>>2)*16 + (l>>4)*4 + (v&3)];
    }
  }
  #undef LOADA3

  if (l < 32) {
    size_t o = ((size_t)(qw0 + l)*NRANGE + rg)*KNN;
    for (int k = 0; k < KNN; k++) {
      float md = rd[0]; int mi = ri[0]; int mp = 0;
      #pragma unroll
      for (int t = 1; t < KNN; t++) {
        bool g = (rd[t] < md) || (rd[t] == md && ri[t] < mi);
        md = g ? rd[t] : md; mi = g ? ri[t] : mi; mp = g ? t : mp;
      }
      pd[o+k] = md; pi[o+k] = mi;
      #pragma unroll
      for (int t = 0; t < KNN; t++) if (t == mp) rd[t] = INFINITY;
    }
  }
}

// ---------------- merge NRANGE sorted partial lists -> top-20 ----------------
__global__ void knn_merge_kernel(const float* __restrict__ pd, const int* __restrict__ pi,
                                 int* __restrict__ out_idx) {
  int qi = blockIdx.x*256 + threadIdx.x;
  const float* bd = pd + (size_t)qi*NRANGE*KNN;
  const int*   bi = pi + (size_t)qi*NRANGE*KNN;
  int ptr[NRANGE];
  #pragma unroll
  for (int r=0;r<NRANGE;r++) ptr[r] = 0;
  for (int k = 0; k < KNN; k++) {
    float best = INFINITY; int besti = 0x7fffffff; int br = 0;
    #pragma unroll
    for (int r = 0; r < NRANGE; r++) {
      float d = bd[r*KNN + ptr[r]];
      int   ii = bi[r*KNN + ptr[r]];
      bool better = (ptr[r] < KNN) && (d < best || (d == best && ii < besti));
      if (better) { best = d; besti = ii; br = r; }
    }
    #pragma unroll
    for (int r=0;r<NRANGE;r++) ptr[r] += (r == br) ? 1 : 0;
    out_idx[qi*KNN + k] = besti;
  }
}

// ---------------- edge_conv1 precompute ----------------
__global__ void cg1_kernel(const float* __restrict__ x, const float* __restrict__ W1,
                           const float* __restrict__ b1,
                           float* __restrict__ C1, float* __restrict__ G1) {
  int gid = blockIdx.x*256 + threadIdx.x;   // 16384*64
  int i = gid >> 6, c = gid & 63;
  float x0 = x[i*3+0], x1 = x[i*3+1], x2 = x[i*3+2];
  float wt0 = W1[0*64+c], wt1 = W1[1*64+c], wt2 = W1[2*64+c];
  float wb0 = W1[3*64+c], wb1 = W1[4*64+c], wb2 = W1[5*64+c];
  C1[gid] = x0*(wt0-wb0) + x1*(wt1-wb1) + x2*(wt2-wb2) + b1[c];
  G1[gid] = x0*wb0 + x1*wb1 + x2*wb2;
}

// ---------------- gather + max + relu ----------------
template<int C>
__global__ void maxrelu_kernel(const float* __restrict__ Ci, const float* __restrict__ G,
                               const int* __restrict__ idx, float* __restrict__ out) {
  int gid = blockIdx.x*256 + threadIdx.x;
  int i = gid / C, c = gid % C;
  float base = Ci[gid];
  float m = -INFINITY;
  for (int j=0; j<KNN; j++) {
    int jj = idx[i*KNN + j];
    m = fmaxf(m, base + G[(long)jj*C + c]);
  }
  out[gid] = fmaxf(m, 0.0f);
}

// ---------------- W2 diff ----------------
__global__ void wd2_kernel(const float* __restrict__ W2, float* __restrict__ Wd) {
  int gid = blockIdx.x*256 + threadIdx.x;   // 64*128
  int d = gid >> 7, c = gid & 127;
  Wd[gid] = W2[d*128+c] - W2[(d+64)*128+c];
}

// ---------------- edge_conv2 precompute ----------------
__global__ void cg2_kernel(const float* __restrict__ h1, const float* __restrict__ W2,
                           const float* __restrict__ Wd, const float* __restrict__ b2,
                           float* __restrict__ C2, float* __restrict__ G2) {
  int gid = blockIdx.x*256 + threadIdx.x;   // 16384*128
  int i = gid >> 7, c = gid & 127;
  float a = 0.f, g = 0.f;
  for (int d=0; d<64; d++) {
    float hv = h1[i*64 + d];
    a += hv * Wd[d*128 + c];
    g += hv * W2[(d+64)*128 + c];
  }
  C2[gid] = a + b2[c];
  G2[gid] = g;
}

// ---------------- fc1 (relu) ----------------
__global__ void fc1_kernel(const float* __restrict__ h2, const float* __restrict__ w,
                           const float* __restrict__ b, float* __restrict__ out) {
  int gid = blockIdx.x*256 + threadIdx.x;   // 16384*128
  int i = gid >> 7, c = gid & 127;
  float a = 0.f;
  for (int d=0; d<128; d++) a += h2[i*128+d] * w[d*128+c];
  out[gid] = fmaxf(a + b[c], 0.0f);
}

// ---------------- fc2 ----------------
__global__ void fc2_kernel(const float* __restrict__ f1, const float* __restrict__ w,
                           const float* __restrict__ b, float* __restrict__ out) {
  int gid = blockIdx.x*256 + threadIdx.x;   // 16384*40
  int i = gid / 40, c = gid - i*40;
  float a = 0.f;
  for (int d=0; d<128; d++) a += f1[i*128+d] * w[d*40+c];
  out[gid] = a + b[c];
}

extern "C" void kernel_launch(void* const* d_in, const int* in_sizes, int n_in,
                              void* d_out, int out_size, void* d_ws, size_t ws_size,
                              hipStream_t stream) {
  (void)in_sizes; (void)n_in; (void)out_size; (void)ws_size;
  const float* x     = (const float*)d_in[0];
  const float* W1    = (const float*)d_in[1];
  const float* b1    = (const float*)d_in[2];
  const float* W2    = (const float*)d_in[3];
  const float* b2    = (const float*)d_in[4];
  const float* fc1_w = (const float*)d_in[5];
  const float* fc1_b = (const float*)d_in[6];
  const float* fc2_w = (const float*)d_in[7];
  const float* fc2_b = (const float*)d_in[8];
  float* out = (float*)d_out;

  // ---- workspace (31.03 MB total, lifetime-disjoint aliasing) ----
  char* ws = (char*)d_ws;
  float4* xp4 = (float4*)(ws + 0);          // 262144
  float*  sqh = (float*) (ws + 262144);     // 65536
  int*    idx = (int*)   (ws + 327680);     // 1310720
  float*  Wd2 = (float*) (ws + 1638400);    // 32768
  float*  h1  = (float*) (ws + 1671168);    // 4194304  -> 5865472
  unsigned short* xpa = (unsigned short*)(ws + 1671168); // 1MB, dead before h1 written
  unsigned short* xpb = (unsigned short*)(ws + 2719744); // 1MB, dead before h1 written
  unsigned short* hbh = (unsigned short*)(ws + 5865472); // 2097152 -> 7962624
  float*  wsd = (float*) (ws + 10059776);   // 65536    (aliases h2-tail; dead then)
  float*  h2  = (float*) (ws + 5865472);    // 8388608  -> 14254080
  float*  A   = (float*) (ws + 14254080);   // 8388608  -> 22642688
  float*  C1  = A;
  float*  G1  = (float*) (ws + 14254080 + 4194304);
  float*  C2  = A;
  float*  f1  = A;
  float*  G2  = (float*) (ws + 22642688);   // 8388608  -> 31031296
  int*    pi  = (int*)   (ws + 14254080);   // 5.25MB (aliases A; A dead during knn phases)
  float*  pd  = (float*) (ws + 22642688);   // 5.25MB (aliases G2; G2 dead during knn phases)

  pack3_kernel <<<64,   256, 0, stream>>>(x, xp4);
  packbf3_kernel<<<64,  256, 0, stream>>>(x, xpa, xpb);
  knn3_wq      <<<1024, 128, 0, stream>>>(xp4, xpa, xpb, pd, pi);
  knn_merge_kernel<<<64,256, 0, stream>>>(pd, pi, idx);
  cg1_kernel   <<<4096, 256, 0, stream>>>(x, W1, b1, C1, G1);
  maxrelu_kernel<64> <<<4096, 256, 0, stream>>>(C1, G1, idx, h1);
  tobf16_kernel<<<1024, 256, 0, stream>>>(h1, hbh);
  sq64_kernel  <<<64,   256, 0, stream>>>(h1, sqh);
  seed64_kernel<<<64,   256, 0, stream>>>(h1, sqh, idx, wsd);
  knn64_wq     <<<1024, 128, 0, stream>>>(h1, hbh, sqh, wsd, pd, pi);
  knn_merge_kernel<<<64,256, 0, stream>>>(pd, pi, idx);
  wd2_kernel   <<<32,   256, 0, stream>>>(W2, Wd2);
  cg2_kernel   <<<8192, 256, 0, stream>>>(h1, W2, Wd2, b2, C2, G2);
  maxrelu_kernel<128><<<8192, 256, 0, stream>>>(C2, G2, idx, h2);
  fc1_kernel   <<<8192, 256, 0, stream>>>(h2, fc1_w, fc1_b, f1);
  fc2_kernel   <<<2560, 256, 0, stream>>>(f1, fc2_w, fc2_b, out);
}